// Round 6
// baseline (350.861 us; speedup 1.0000x reference)
//
#include <hip/hip_runtime.h>
#include <cstdint>
#include <cstddef>

// ---------------- problem constants ----------------
// B=16, L=128, E=256, H=256, RR=128, BIO=64, NT=3, V=30000, R=25

typedef __attribute__((ext_vector_type(8))) short short8;
typedef __attribute__((ext_vector_type(8))) int i32x8;
typedef __attribute__((ext_vector_type(4))) float f32x4;

__device__ __forceinline__ unsigned short f2bf(float f) {
  unsigned int u = __float_as_uint(f);
  u += 0x7fffu + ((u >> 16) & 1u);
  return (unsigned short)(u >> 16);
}
__device__ __forceinline__ float bf2f(unsigned short u) {
  return __uint_as_float(((unsigned int)u) << 16);
}

// ---------------- setup: weight prepacks + acc init ----------------
__device__ __forceinline__ void dev_pp8k128(const float* __restrict__ W,
                                            unsigned int* __restrict__ out, int idx) {
  int c = idx & 3;
  int lane = (idx >> 2) & 63;
  int f = idx >> 8;
  int nt = f >> 1, kt = f & 1;
  int n = nt * 16 + (lane & 15);
  int k0 = kt * 128 + (lane >> 4) * 32 + c * 8;
  const float* wp = &W[(size_t)n * 256 + k0];
  int lo = 0, hi = 0;
  lo = __builtin_amdgcn_cvt_pk_fp8_f32(wp[0], wp[1], lo, false);
  lo = __builtin_amdgcn_cvt_pk_fp8_f32(wp[2], wp[3], lo, true);
  hi = __builtin_amdgcn_cvt_pk_fp8_f32(wp[4], wp[5], hi, false);
  hi = __builtin_amdgcn_cvt_pk_fp8_f32(wp[6], wp[7], hi, true);
  size_t base = ((size_t)(f << 6) + lane) * 8 + (c << 1);
  out[base] = (unsigned)lo;
  out[base + 1] = (unsigned)hi;
}

__device__ __forceinline__ void dev_ppw(const float* __restrict__ W, int ldw, int nkt,
                                        uint4* __restrict__ out, int idx) {
  int lane = idx & 63;
  int f = idx >> 6;
  int kt = f % nkt;
  int nt = f / nkt;
  int row = nt * 16 + (lane & 15);
  int k0 = kt * 32 + ((lane >> 4) << 3);
  const float* wp = &W[(size_t)row * ldw + k0];
  union { unsigned short us[8]; uint4 v; } tmp;
#pragma unroll
  for (int j = 0; j < 8; ++j) tmp.us[j] = f2bf(wp[j]);
  out[idx] = tmp.v;
}

__global__ __launch_bounds__(256) void k_setup(
    const float* __restrict__ Whhf, unsigned int* __restrict__ wpk8f,
    const float* __restrict__ Whhb, unsigned int* __restrict__ wpk8b,
    const float* __restrict__ Wihf, uint4* __restrict__ wihfPk,
    const float* __restrict__ Wihb, uint4* __restrict__ wihbPk,
    const float* __restrict__ suW, uint4* __restrict__ suPk,
    const float* __restrict__ svW, uint4* __restrict__ svPk,
    const float* __restrict__ suvW, uint4* __restrict__ w1Pk, uint4* __restrict__ w2Pk,
    float* __restrict__ acc) {
  int bid = blockIdx.x;
  int t = threadIdx.x;
  if (bid < 128) {
    dev_pp8k128(Whhf, wpk8f, bid * 256 + t);
  } else if (bid < 256) {
    dev_pp8k128(Whhb, wpk8b, (bid - 128) * 256 + t);
  } else if (bid < 384) {
    dev_ppw(Wihf, 256, 8, wihfPk, (bid - 256) * 256 + t);
  } else if (bid < 512) {
    dev_ppw(Wihb, 256, 8, wihbPk, (bid - 384) * 256 + t);
  } else if (bid < 532) {
    dev_ppw(suW, 320, 10, suPk, (bid - 512) * 256 + t);
  } else if (bid < 552) {
    dev_ppw(svW, 320, 10, svPk, (bid - 532) * 256 + t);
  } else if (bid < 560) {
    dev_ppw(suvW, 256, 4, w1Pk, (bid - 552) * 256 + t);
  } else if (bid < 568) {
    dev_ppw(suvW + 128, 256, 4, w2Pk, (bid - 560) * 256 + t);
  } else {
    if (t < 16) acc[t] = 0.f;
  }
}

// ---------------- xg GEMM v2: 16 rows x 1024 cols per block, coalesced P-pack ----
__global__ __launch_bounds__(256) void k_xg(
    const int* __restrict__ tok, const float* __restrict__ wemb,
    const uint4* __restrict__ WpkF, const float* __restrict__ biasF,
    unsigned short* __restrict__ PF,
    const uint4* __restrict__ WpkB, const float* __restrict__ biasB,
    unsigned short* __restrict__ PB) {
  const uint4* Wp = blockIdx.y ? WpkB : WpkF;
  const float* bi = blockIdx.y ? biasB : biasF;
  unsigned short* Po = blockIdx.y ? PB : PF;
  __shared__ __align__(16) unsigned short oc[16][1024];
  int r0 = blockIdx.x * 16;
  int tid = threadIdx.x;
  int w = tid >> 6;
  int lane = tid & 63;
  int m = lane & 15;
  int q = lane >> 4;
  const float* ew = wemb + (size_t)tok[r0 + m] * 256 + (q << 3);
  f32x4 z = {0.f, 0.f, 0.f, 0.f};
  f32x4 ac[16] = {z, z, z, z, z, z, z, z, z, z, z, z, z, z, z, z};
  for (int kt = 0; kt < 8; ++kt) {
    float4 e0 = *reinterpret_cast<const float4*>(ew + (kt << 5));
    float4 e1 = *reinterpret_cast<const float4*>(ew + (kt << 5) + 4);
    union { unsigned short us[8]; short8 v; } af;
    af.us[0] = f2bf(e0.x); af.us[1] = f2bf(e0.y); af.us[2] = f2bf(e0.z); af.us[3] = f2bf(e0.w);
    af.us[4] = f2bf(e1.x); af.us[5] = f2bf(e1.y); af.us[6] = f2bf(e1.z); af.us[7] = f2bf(e1.w);
#pragma unroll
    for (int j = 0; j < 16; ++j) {
      int nt = (w << 4) + j;
      uint4 b4 = Wp[(size_t)(nt * 8 + kt) * 64 + lane];
      ac[j] = __builtin_amdgcn_mfma_f32_16x16x32_bf16(af.v, __builtin_bit_cast(short8, b4), ac[j], 0, 0, 0);
    }
  }
  // stage into P-packed LDS tile: for wave w, g = w
#pragma unroll
  for (int j = 0; j < 16; ++j) {
    int col = (w << 8) + (j << 4) + m;
    float bv = bi[col];
    int cellp = ((j >> 1) << 4) | m;          // (wl<<4)|mm
    int sub = (w << 1) | (j & 1);             // (g<<1)|nn
#pragma unroll
    for (int reg = 0; reg < 4; ++reg) {
      int row = (q << 2) + reg;
      oc[row][(cellp << 3) + sub] = f2bf(ac[j][reg] + bv);
    }
  }
  __syncthreads();
  // coalesced copy-out: 16 rows x 2KB
  int b = r0 >> 7;
  unsigned short* Pb = Po + ((size_t)b << 17);
#pragma unroll
  for (int i = 0; i < 8; ++i) {
    int idx = i * 256 + tid;
    int row = idx >> 7;
    int c8 = idx & 127;
    uint4 v = *reinterpret_cast<const uint4*>(&oc[row][c8 << 3]);
    int t = (r0 + row) & 127;
    *reinterpret_cast<uint4*>(Pb + ((size_t)t << 10) + (c8 << 3)) = v;
  }
}

// ---------------- LSTM v15: half-barrier split-h pipeline ----------------
// 32 blocks = (dir,b), 512 thr = 8 waves; wave w owns cells [32w,32w+32).
// Waves 0-3 produce h-low (cells 0..127 = afr[0] K-range); waves 4-7 h-high.
// Two barriers per step: BarL (h-low(s) visible), BarH (h-high(s) visible).
//  low waves:  MFMA -> gates -> write low -> lgkm -> BarL -> read afr0' ->
//              BarH -> read afr1'
//  high waves: MFMA -> BarL (arrive early, nothing owed) -> read afr0' ->
//              gates -> write high -> lgkm -> BarH -> read afr1'
// High waves' gates + everyone's afr0 reads overlap the barrier chain instead
// of serializing after one block-wide barrier. Numerics bit-identical to v14.
__global__ __launch_bounds__(512, 2) void k_lstm(
    const unsigned short* __restrict__ Pf, const unsigned short* __restrict__ Pb,
    const unsigned int* __restrict__ wpkf, const unsigned int* __restrict__ wpkb,
    unsigned short* __restrict__ hsf, unsigned short* __restrict__ hsb) {
  int bid = blockIdx.x;
  int dir = bid >> 4;
  int b = bid & 15;
  const unsigned short* P = (dir ? Pb : Pf) + ((size_t)b << 17);
  const unsigned int* wpk = dir ? wpkb : wpkf;
  unsigned short* hseq = (dir ? hsb : hsf) + (size_t)b * 128 * 256;

  __shared__ __align__(16) unsigned char h8[2][272];   // fp8 h, double-buffered

  int tid = threadIdx.x;
  int w = tid >> 6;
  int lane = tid & 63;
  int m = lane & 15;
  int q = lane >> 4;
  int nsel = q & 1;
  int jj = (w << 5) + m + (nsel << 4);   // the cell this lane's gate chain owns
  bool lowg = (w < 4);                    // wave-uniform

  // resident weights: 16 x i32x8 = 128 regs/lane (AGPR)
  i32x8 wfr[4][2][2];
#pragma unroll
  for (int g = 0; g < 4; ++g)
#pragma unroll
    for (int n = 0; n < 2; ++n)
#pragma unroll
      for (int kt = 0; kt < 2; ++kt) {
        int f = (((g << 4) + (w << 1) + n) << 1) + kt;
        wfr[g][n][kt] = *reinterpret_cast<const i32x8*>(wpk + (((size_t)(f << 6) + lane) << 3));
      }
#pragma unroll
  for (int g = 0; g < 4; ++g)
#pragma unroll
    for (int n = 0; n < 2; ++n)
#pragma unroll
      for (int kt = 0; kt < 2; ++kt)
        asm volatile("" : "+v"(wfr[g][n][kt]));

  if (tid < 136) reinterpret_cast<unsigned int*>(&h8[0][0])[tid] = 0u;
  __syncthreads();

  const f32x4 zero4 = {0.f, 0.f, 0.f, 0.f};
  float cst = 0.f;                       // c-state of cell jj

  // x loader: lane's 16B packet for step s (same addr across q -> broadcast)
  auto load_x = [&](int s) -> uint4 {
    int t = dir ? (127 - (s & 127)) : (s & 127);
    return *reinterpret_cast<const uint4*>(
        P + ((size_t)((t << 7) + (w << 4) + m) << 3));
  };

  // loop-carried A-frags (h(s-1)); initial = zeros from h8[0]
  i32x8 afr0, afr1;
  {
    const unsigned char* cur = &h8[0][0];
    union { uint4 u[2]; i32x8 v; } t0, t1;
    t0.u[0] = *reinterpret_cast<const uint4*>(cur + q * 32);
    t0.u[1] = *reinterpret_cast<const uint4*>(cur + q * 32 + 16);
    t1.u[0] = *reinterpret_cast<const uint4*>(cur + 128 + q * 32);
    t1.u[1] = *reinterpret_cast<const uint4*>(cur + 128 + q * 32 + 16);
    afr0 = t0.v;
    afr1 = t1.v;
  }

  auto gates = [&](const f32x4 acg[4][2], uint4 x4, int t,
                   unsigned char* nxt) {
    unsigned u0 = x4.x, u1 = x4.y, u2 = x4.z, u3 = x4.w;
    float x0 = __uint_as_float(nsel ? (u0 & 0xffff0000u) : (u0 << 16));
    float x1 = __uint_as_float(nsel ? (u1 & 0xffff0000u) : (u1 << 16));
    float x2 = __uint_as_float(nsel ? (u2 & 0xffff0000u) : (u2 << 16));
    float x3 = __uint_as_float(nsel ? (u3 & 0xffff0000u) : (u3 << 16));
    float gi = (nsel ? acg[0][1][0] : acg[0][0][0]) + x0;
    float gf = (nsel ? acg[1][1][0] : acg[1][0][0]) + x1;
    float gg = (nsel ? acg[2][1][0] : acg[2][0][0]) + x2;
    float go = (nsel ? acg[3][1][0] : acg[3][0][0]) + x3;
    float si = __fdividef(1.f, 1.f + __expf(-gi));
    float sf = __fdividef(1.f, 1.f + __expf(-gf));
    float so = __fdividef(1.f, 1.f + __expf(-go));
    float tg = 1.f - __fdividef(2.f, __expf(2.f * gg) + 1.f);
    float cc = sf * cst + si * tg;
    cst = cc;
    float th = 1.f - __fdividef(2.f, __expf(2.f * cc) + 1.f);
    float h = so * th;
    if (q < 2) {
      hseq[(size_t)t * 256 + jj] = f2bf(h);
      int pk = __builtin_amdgcn_cvt_pk_fp8_f32(h, h, 0, false);
      nxt[jj] = (unsigned char)(pk & 0xff);
    }
  };

  auto step = [&](int s, uint4 x4) {
    int t = dir ? (127 - s) : s;
    unsigned char* nxt = &h8[(s & 1) ^ 1][0];

    f32x4 acg[4][2];
#pragma unroll
    for (int n = 0; n < 2; ++n) {
#pragma unroll
      for (int g = 0; g < 4; ++g)
        acg[g][n] = __builtin_amdgcn_mfma_scale_f32_16x16x128_f8f6f4(
            afr0, wfr[g][n][0], zero4, 0, 0, 0, 0x7f7f7f7f, 0, 0x7f7f7f7f);
#pragma unroll
      for (int g = 0; g < 4; ++g)
        acg[g][n] = __builtin_amdgcn_mfma_scale_f32_16x16x128_f8f6f4(
            afr1, wfr[g][n][1], acg[g][n], 0, 0, 0, 0x7f7f7f7f, 0, 0x7f7f7f7f);
    }

    if (lowg) {
      // low waves: finish gates, publish h-low, then BarL
      gates(acg, x4, t, nxt);
      asm volatile("s_waitcnt lgkmcnt(0)" ::: "memory");
      __builtin_amdgcn_s_barrier();                       // BarL
      asm volatile("" ::: "memory");
      union { uint4 u[2]; i32x8 v; } t0;
      t0.u[0] = *reinterpret_cast<const uint4*>(nxt + q * 32);
      t0.u[1] = *reinterpret_cast<const uint4*>(nxt + q * 32 + 16);
      asm volatile("" ::: "memory");
      __builtin_amdgcn_s_barrier();                       // BarH
      asm volatile("" ::: "memory");
      union { uint4 u[2]; i32x8 v; } t1;
      t1.u[0] = *reinterpret_cast<const uint4*>(nxt + 128 + q * 32);
      t1.u[1] = *reinterpret_cast<const uint4*>(nxt + 128 + q * 32 + 16);
      afr0 = t0.v;
      afr1 = t1.v;
    } else {
      // high waves: arrive at BarL immediately (nothing owed), overlap
      // afr0 read + gates with the barrier chain, publish h-high, BarH
      asm volatile("" ::: "memory");
      __builtin_amdgcn_s_barrier();                       // BarL
      asm volatile("" ::: "memory");
      union { uint4 u[2]; i32x8 v; } t0;
      t0.u[0] = *reinterpret_cast<const uint4*>(nxt + q * 32);
      t0.u[1] = *reinterpret_cast<const uint4*>(nxt + q * 32 + 16);
      gates(acg, x4, t, nxt);
      asm volatile("s_waitcnt lgkmcnt(0)" ::: "memory");
      __builtin_amdgcn_s_barrier();                       // BarH
      asm volatile("" ::: "memory");
      union { uint4 u[2]; i32x8 v; } t1;
      t1.u[0] = *reinterpret_cast<const uint4*>(nxt + 128 + q * 32);
      t1.u[1] = *reinterpret_cast<const uint4*>(nxt + 128 + q * 32 + 16);
      afr0 = t0.v;
      afr1 = t1.v;
    }
  };

  uint4 xA = load_x(0);
  for (int sp = 0; sp < 128; sp += 2) {
    uint4 xB = load_x(sp + 1);
    step(sp, xA);
    xA = load_x(sp + 2);     // wraps via &127; harmless dummy on last iter
    step(sp + 1, xB);
  }
}

// ---------------- mid v2: 128 blocks x 16 rows: oc -> emi, u,v -> a,c ----------------
__global__ __launch_bounds__(256) void k_mid2(
    const unsigned short* __restrict__ hf16, const unsigned short* __restrict__ hb16,
    const int* __restrict__ bio, const float* __restrict__ bioE,
    const float* __restrict__ emiW, const float* __restrict__ emib,
    const uint4* __restrict__ suPk, const float* __restrict__ sub,
    const uint4* __restrict__ svPk, const float* __restrict__ svb,
    const uint4* __restrict__ w1Pk, const uint4* __restrict__ w2Pk,
    unsigned short* __restrict__ a16, unsigned short* __restrict__ c16,
    float* __restrict__ emi) {
  __shared__ __align__(16) unsigned short oc[16][328];
  __shared__ __align__(16) unsigned short ub[16][136];
  __shared__ __align__(16) unsigned short vb[16][136];
  int r0 = blockIdx.x * 16;
  int tid = threadIdx.x;

#pragma unroll
  for (int it = 0; it < 8; ++it) {
    int i = it * 256 + tid;
    int row = i >> 7, h2 = (i & 127) << 1;
    unsigned int af = *reinterpret_cast<const unsigned int*>(hf16 + (size_t)(r0 + row) * 256 + h2);
    unsigned int ab = *reinterpret_cast<const unsigned int*>(hb16 + (size_t)(r0 + row) * 256 + h2);
    float lo = 0.5f * (bf2f((unsigned short)af) + bf2f((unsigned short)ab));
    float hi = 0.5f * (bf2f((unsigned short)(af >> 16)) + bf2f((unsigned short)(ab >> 16)));
    unsigned int pk = (unsigned int)f2bf(lo) | ((unsigned int)f2bf(hi) << 16);
    *reinterpret_cast<unsigned int*>(&oc[row][h2]) = pk;
  }
#pragma unroll
  for (int it = 0; it < 2; ++it) {
    int i = it * 256 + tid;
    int row = i >> 5, p = (i & 31) << 1;
    int bi = bio[r0 + row];
    float b0 = bioE[bi * 64 + p], b1 = bioE[bi * 64 + p + 1];
    unsigned int pk = (unsigned int)f2bf(b0) | ((unsigned int)f2bf(b1) << 16);
    *reinterpret_cast<unsigned int*>(&oc[row][256 + p]) = pk;
  }
  __syncthreads();

  if (tid < 192) {
    int did = tid >> 2, sub4 = tid & 3;
    int row = did / 3, g = did - row * 3;
    const float* ew = emiW + g * 256 + sub4 * 64;
    float av = 0.f;
#pragma unroll
    for (int k = 0; k < 64; ++k) av += bf2f(oc[row][sub4 * 64 + k]) * ew[k];
    av += __shfl_xor(av, 1);
    av += __shfl_xor(av, 2);
    if (sub4 == 0) emi[(size_t)(r0 + row) * 3 + g] = av + emib[g];
  }

  int w = tid >> 6, lane = tid & 63, m = lane & 15, q = lane >> 4;
  {
    f32x4 z = {0.f, 0.f, 0.f, 0.f};
    f32x4 au[2] = {z, z}, av2[2] = {z, z};
    for (int kt = 0; kt < 10; ++kt) {
      uint4 a4 = *reinterpret_cast<const uint4*>(&oc[m][(kt << 5) + (q << 3)]);
      short8 af = __builtin_bit_cast(short8, a4);
#pragma unroll
      for (int d = 0; d < 2; ++d) {
        int nt = (w << 1) + d;
        uint4 bu = suPk[(size_t)(nt * 10 + kt) * 64 + lane];
        uint4 bv = svPk[(size_t)(nt * 10 + kt) * 64 + lane];
        au[d] = __builtin_amdgcn_mfma_f32_16x16x32_bf16(af, __builtin_bit_cast(short8, bu), au[d], 0, 0, 0);
        av2[d] = __builtin_amdgcn_mfma_f32_16x16x32_bf16(af, __builtin_bit_cast(short8, bv), av2[d], 0, 0, 0);
      }
    }
#pragma unroll
    for (int d = 0; d < 2; ++d) {
      int col = ((w << 1) + d) * 16 + m;
      float bu = sub[col], bv = svb[col];
#pragma unroll
      for (int reg = 0; reg < 4; ++reg) {
        int row = (q << 2) + reg;
        ub[row][col] = f2bf(fmaxf(au[d][reg] + bu, 0.f));
        vb[row][col] = f2bf(fmaxf(av2[d][reg] + bv, 0.f));
      }
    }
  }
  __syncthreads();

  {
    f32x4 z = {0.f, 0.f, 0.f, 0.f};
    f32x4 aa[2] = {z, z}, cc[2] = {z, z};
    for (int kt = 0; kt < 4; ++kt) {
      uint4 ua = *reinterpret_cast<const uint4*>(&ub[m][(kt << 5) + (q << 3)]);
      uint4 va = *reinterpret_cast<const uint4*>(&vb[m][(kt << 5) + (q << 3)]);
      short8 uf = __builtin_bit_cast(short8, ua);
      short8 vf = __builtin_bit_cast(short8, va);
#pragma unroll
      for (int d = 0; d < 2; ++d) {
        int nt = (w << 1) + d;
        uint4 b1 = w1Pk[(size_t)((nt << 2) + kt) * 64 + lane];
        uint4 b2 = w2Pk[(size_t)((nt << 2) + kt) * 64 + lane];
        aa[d] = __builtin_amdgcn_mfma_f32_16x16x32_bf16(uf, __builtin_bit_cast(short8, b1), aa[d], 0, 0, 0);
        cc[d] = __builtin_amdgcn_mfma_f32_16x16x32_bf16(vf, __builtin_bit_cast(short8, b2), cc[d], 0, 0, 0);
      }
    }
#pragma unroll
    for (int d = 0; d < 2; ++d) {
      int col = ((w << 1) + d) * 16 + m;
#pragma unroll
      for (int reg = 0; reg < 4; ++reg) {
        int row = r0 + (q << 2) + reg;
        a16[(size_t)row * 128 + col] = f2bf(aa[d][reg]);
        c16[(size_t)row * 128 + col] = f2bf(cc[d][reg]);
      }
    }
  }
}

// ---------------- fused loss: sel (0..1023) + crf (1024..1039) + finalize ----------
__global__ __launch_bounds__(256) void k_loss(
    const unsigned short* __restrict__ a16, const unsigned short* __restrict__ c16,
    const float* __restrict__ suvb, const float* __restrict__ rel,
    const float* __restrict__ y, const int* __restrict__ tok,
    const float* __restrict__ emi, const int* __restrict__ bio,
    const float* __restrict__ cstart, const float* __restrict__ cend,
    const float* __restrict__ ctrans,
    float* __restrict__ acc, float* __restrict__ out) {
  int blk = blockIdx.x;
  int tid = threadIdx.x;
  if (blk < 1024) {
    __shared__ unsigned short alds[128][136];
    __shared__ float cbs[2][128];
    __shared__ float red[4];
    int b = blk >> 6;
    int ip = blk & 63;
    int hh = tid & 127;
    int half = tid >> 7;
#pragma unroll
    for (int it = 0; it < 32; ++it) {
      int idx = it * 256 + tid;
      int jrow = idx >> 6;
      int h2 = (idx & 63) << 1;
      unsigned int av = *reinterpret_cast<const unsigned int*>(
          a16 + ((size_t)(b << 7) + jrow) * 128 + h2);
      alds[h2][jrow] = (unsigned short)av;
      alds[h2 + 1][jrow] = (unsigned short)(av >> 16);
    }
    {
      int i = (ip << 1) + half;
      cbs[half][hh] = bf2f(c16[(size_t)((b << 7) + i) * 128 + hh]) + suvb[hh];
    }
    __syncthreads();
    int i = (ip << 1) + half;
    int j = hh;
    float lg[25];
#pragma unroll
    for (int r = 0; r < 25; ++r) lg[r] = 0.f;
    for (int h = 0; h < 128; ++h) {
      float av = bf2f(alds[h][j]);
      float uv = fmaxf(av + cbs[half][h], 0.f);
#pragma unroll
      for (int r = 0; r < 25; ++r) lg[r] += uv * rel[r * 128 + h];
    }
    float mi = (tok[(b << 7) + i] != 0) ? 1.f : 0.f;
    float mj = (tok[(b << 7) + j] != 0) ? 1.f : 0.f;
    const float* yp = y + (size_t)((b << 7) + i) * 3200 + j;
    float bs = 0.f;
#pragma unroll
    for (int r = 0; r < 25; ++r) {
      float x = lg[r];
      float yv = yp[r * 128];
      bs += fmaxf(x, 0.f) - x * yv + __logf(1.f + __expf(-fabsf(x)));
    }
    bs *= mi * mj;
#pragma unroll
    for (int off = 32; off; off >>= 1) bs += __shfl_down(bs, off);
    if ((tid & 63) == 0) red[tid >> 6] = bs;
    __syncthreads();
    if (tid == 0) atomicAdd(&acc[0], red[0] + red[1] + red[2] + red[3]);
  } else {
    __shared__ float elds[128][4];
    __shared__ float msk[128];
    __shared__ int biol[128];
    __shared__ float r_t[2], r_m[2];
    int b = blk - 1024;
    int t = tid;
    if (t < 128) {
      biol[t] = bio[b * 128 + t];
      msk[t] = (tok[b * 128 + t] != 0) ? 1.f : 0.f;
#pragma unroll
      for (int g = 0; g < 3; ++g) elds[t][g] = emi[(b * 128 + t) * 3 + g];
    }
    __syncthreads();
    if (t < 128) {
      float m = msk[t];
      float term;
      if (t == 0)
        term = cstart[biol[0]] + elds[0][biol[0]];
      else
        term = (ctrans[biol[t - 1] * 3 + biol[t]] + elds[t][biol[t]]) * m;
      float ms = m;
#pragma unroll
      for (int off = 32; off; off >>= 1) {
        term += __shfl_down(term, off);
        ms += __shfl_down(ms, off);
      }
      if ((t & 63) == 0) { r_t[t >> 6] = term; r_m[t >> 6] = ms; }
    }
    __syncthreads();
    if (t == 0) {
      float num = r_t[0] + r_t[1];
      float msum = r_m[0] + r_m[1];
      int se = (int)msum - 1;
      if (se < 0) se = 0;
      num += cend[biol[se]];
      float tr[9];
#pragma unroll
      for (int i2 = 0; i2 < 9; ++i2) tr[i2] = ctrans[i2];
      float s0 = cstart[0] + elds[0][0];
      float s1 = cstart[1] + elds[0][1];
      float s2 = cstart[2] + elds[0][2];
      for (int tt = 1; tt < 128; ++tt) {
        float a0, a1, a2, mx, n0, n1, n2;
        a0 = s0 + tr[0]; a1 = s1 + tr[3]; a2 = s2 + tr[6];
        mx = fmaxf(a0, fmaxf(a1, a2));
        n0 = mx + __logf(__expf(a0 - mx) + __expf(a1 - mx) + __expf(a2 - mx)) + elds[tt][0];
        a0 = s0 + tr[1]; a1 = s1 + tr[4]; a2 = s2 + tr[7];
        mx = fmaxf(a0, fmaxf(a1, a2));
        n1 = mx + __logf(__expf(a0 - mx) + __expf(a1 - mx) + __expf(a2 - mx)) + elds[tt][1];
        a0 = s0 + tr[2]; a1 = s1 + tr[5]; a2 = s2 + tr[8];
        mx = fmaxf(a0, fmaxf(a1, a2));
        n2 = mx + __logf(__expf(a0 - mx) + __expf(a1 - mx) + __expf(a2 - mx)) + elds[tt][2];
        if (msk[tt] != 0.f) { s0 = n0; s1 = n1; s2 = n2; }
      }
      float a0 = s0 + cend[0], a1 = s1 + cend[1], a2 = s2 + cend[2];
      float mx = fmaxf(a0, fmaxf(a1, a2));
      float den = mx + __logf(__expf(a0 - mx) + __expf(a1 - mx) + __expf(a2 - mx));
      atomicAdd(&acc[1], num - den);
      atomicAdd(&acc[2], msum);
    }
  }
  if (tid == 0) {
    __threadfence();
    unsigned old = atomicAdd((unsigned int*)(acc + 5), 1u);
    if (old == 1039u) {
      __threadfence();
      float s0 = atomicAdd(&acc[0], 0.f);
      float s1 = atomicAdd(&acc[1], 0.f);
      float s2 = atomicAdd(&acc[2], 0.f);
      out[0] = -(s1 * (1.f / 16.f)) + s0 / s2;
    }
  }
}

// ---------------- host launcher ----------------
extern "C" void kernel_launch(void* const* d_in, const int* in_sizes, int n_in,
                              void* d_out, int out_size, void* d_ws, size_t ws_size,
                              hipStream_t stream) {
  const int* tokens = (const int*)d_in[0];
  const int* bio = (const int*)d_in[1];
  const float* selg = (const float*)d_in[2];
  const float* wemb = (const float*)d_in[3];
  const float* Wihf = (const float*)d_in[4];
  const float* Whhf = (const float*)d_in[5];
  const float* bf = (const float*)d_in[6];
  const float* Wihb = (const float*)d_in[7];
  const float* Whhb = (const float*)d_in[8];
  const float* bb = (const float*)d_in[9];
  const float* emiW = (const float*)d_in[10];
  const float* emib = (const float*)d_in[11];
  const float* bioE = (const float*)d_in[12];
  const float* suW = (const float*)d_in[13];
  const float* sub = (const float*)d_in[14];
  const float* svW = (const float*)d_in[15];
  const float* svb = (const float*)d_in[16];
  const float* suvW = (const float*)d_in[17];
  const float* suvb = (const float*)d_in[18];
  const float* rel = (const float*)d_in[19];
  const float* cstart = (const float*)d_in[20];
  const float* cend = (const float*)d_in[21];
  const float* ctrans = (const float*)d_in[22];

  float* ws = (float*)d_ws;
  float* xgf16 = ws;                         // 1048576 f = 4MB: P-packed xg fwd
  float* xgb16 = xgf16 + 1048576;            // P-packed xg bwd
  float* hf16 = xgb16 + 1048576;             // 262144 f (2048x256 bf16)
  float* hb16 = hf16 + 262144;               // 262144
  float* a16 = hb16 + 262144;                // 131072 f (2048x128 bf16)
  float* c16 = a16 + 131072;                 // 131072
  float* emi = c16 + 131072;                 // 6144
  float* wpk8f = emi + 6144;                 // 65536 f (256 KB fp8 K=128 frags)
  float* wpk8b = wpk8f + 65536;              // 65536
  float* wihfPk = wpk8b + 65536;             // 131072 f
  float* wihbPk = wihfPk + 131072;           // 131072
  float* suPk = wihbPk + 131072;             // 20480 f
  float* svPk = suPk + 20480;                // 20480
  float* w1Pk = svPk + 20480;                // 8192 f
  float* w2Pk = w1Pk + 8192;                 // 8192
  float* acc = w2Pk + 8192;                  // 16

  k_setup<<<569, 256, 0, stream>>>(
      Whhf, (unsigned int*)wpk8f, Whhb, (unsigned int*)wpk8b,
      Wihf, (uint4*)wihfPk, Wihb, (uint4*)wihbPk,
      suW, (uint4*)suPk, svW, (uint4*)svPk,
      suvW, (uint4*)w1Pk, (uint4*)w2Pk, acc);

  k_xg<<<dim3(128, 2), 256, 0, stream>>>(
      tokens, wemb,
      (const uint4*)wihfPk, bf, (unsigned short*)xgf16,
      (const uint4*)wihbPk, bb, (unsigned short*)xgb16);

  k_lstm<<<32, 512, 0, stream>>>(
      (const unsigned short*)xgf16, (const unsigned short*)xgb16,
      (const unsigned int*)wpk8f, (const unsigned int*)wpk8b,
      (unsigned short*)hf16, (unsigned short*)hb16);

  k_mid2<<<128, 256, 0, stream>>>(
      (const unsigned short*)hf16, (const unsigned short*)hb16,
      bio, bioE, emiW, emib,
      (const uint4*)suPk, sub, (const uint4*)svPk, svb,
      (const uint4*)w1Pk, (const uint4*)w2Pk,
      (unsigned short*)a16, (unsigned short*)c16, emi);

  k_loss<<<1040, 256, 0, stream>>>((const unsigned short*)a16, (const unsigned short*)c16,
                                   suvb, rel, selg, tokens, emi, bio,
                                   cstart, cend, ctrans, acc, (float*)d_out);
}

// Round 8
// 335.611 us; speedup vs baseline: 1.0454x; 1.0454x over previous
//
#include <hip/hip_runtime.h>
#include <cstdint>
#include <cstddef>

// ---------------- problem constants ----------------
// B=16, L=128, E=256, H=256, RR=128, BIO=64, NT=3, V=30000, R=25

typedef __attribute__((ext_vector_type(8))) short short8;
typedef __attribute__((ext_vector_type(8))) int i32x8;
typedef __attribute__((ext_vector_type(4))) float f32x4;

__device__ __forceinline__ unsigned short f2bf(float f) {
  unsigned int u = __float_as_uint(f);
  u += 0x7fffu + ((u >> 16) & 1u);
  return (unsigned short)(u >> 16);
}
__device__ __forceinline__ float bf2f(unsigned short u) {
  return __uint_as_float(((unsigned int)u) << 16);
}

// ---------------- setup: weight prepacks + acc init ----------------
__device__ __forceinline__ void dev_pp8k128(const float* __restrict__ W,
                                            unsigned int* __restrict__ out, int idx) {
  int c = idx & 3;
  int lane = (idx >> 2) & 63;
  int f = idx >> 8;
  int nt = f >> 1, kt = f & 1;
  int n = nt * 16 + (lane & 15);
  int k0 = kt * 128 + (lane >> 4) * 32 + c * 8;
  const float* wp = &W[(size_t)n * 256 + k0];
  int lo = 0, hi = 0;
  lo = __builtin_amdgcn_cvt_pk_fp8_f32(wp[0], wp[1], lo, false);
  lo = __builtin_amdgcn_cvt_pk_fp8_f32(wp[2], wp[3], lo, true);
  hi = __builtin_amdgcn_cvt_pk_fp8_f32(wp[4], wp[5], hi, false);
  hi = __builtin_amdgcn_cvt_pk_fp8_f32(wp[6], wp[7], hi, true);
  size_t base = ((size_t)(f << 6) + lane) * 8 + (c << 1);
  out[base] = (unsigned)lo;
  out[base + 1] = (unsigned)hi;
}

__device__ __forceinline__ void dev_ppw(const float* __restrict__ W, int ldw, int nkt,
                                        uint4* __restrict__ out, int idx) {
  int lane = idx & 63;
  int f = idx >> 6;
  int kt = f % nkt;
  int nt = f / nkt;
  int row = nt * 16 + (lane & 15);
  int k0 = kt * 32 + ((lane >> 4) << 3);
  const float* wp = &W[(size_t)row * ldw + k0];
  union { unsigned short us[8]; uint4 v; } tmp;
#pragma unroll
  for (int j = 0; j < 8; ++j) tmp.us[j] = f2bf(wp[j]);
  out[idx] = tmp.v;
}

__global__ __launch_bounds__(256) void k_setup(
    const float* __restrict__ Whhf, unsigned int* __restrict__ wpk8f,
    const float* __restrict__ Whhb, unsigned int* __restrict__ wpk8b,
    const float* __restrict__ Wihf, uint4* __restrict__ wihfPk,
    const float* __restrict__ Wihb, uint4* __restrict__ wihbPk,
    const float* __restrict__ suW, uint4* __restrict__ suPk,
    const float* __restrict__ svW, uint4* __restrict__ svPk,
    const float* __restrict__ suvW, uint4* __restrict__ w1Pk, uint4* __restrict__ w2Pk,
    float* __restrict__ acc) {
  int bid = blockIdx.x;
  int t = threadIdx.x;
  if (bid < 128) {
    dev_pp8k128(Whhf, wpk8f, bid * 256 + t);
  } else if (bid < 256) {
    dev_pp8k128(Whhb, wpk8b, (bid - 128) * 256 + t);
  } else if (bid < 384) {
    dev_ppw(Wihf, 256, 8, wihfPk, (bid - 256) * 256 + t);
  } else if (bid < 512) {
    dev_ppw(Wihb, 256, 8, wihbPk, (bid - 384) * 256 + t);
  } else if (bid < 532) {
    dev_ppw(suW, 320, 10, suPk, (bid - 512) * 256 + t);
  } else if (bid < 552) {
    dev_ppw(svW, 320, 10, svPk, (bid - 532) * 256 + t);
  } else if (bid < 560) {
    dev_ppw(suvW, 256, 4, w1Pk, (bid - 552) * 256 + t);
  } else if (bid < 568) {
    dev_ppw(suvW + 128, 256, 4, w2Pk, (bid - 560) * 256 + t);
  } else {
    if (t < 16) acc[t] = 0.f;
  }
}

// ---------------- xg GEMM v2: 16 rows x 1024 cols per block, coalesced P-pack ----
__global__ __launch_bounds__(256) void k_xg(
    const int* __restrict__ tok, const float* __restrict__ wemb,
    const uint4* __restrict__ WpkF, const float* __restrict__ biasF,
    unsigned short* __restrict__ PF,
    const uint4* __restrict__ WpkB, const float* __restrict__ biasB,
    unsigned short* __restrict__ PB) {
  const uint4* Wp = blockIdx.y ? WpkB : WpkF;
  const float* bi = blockIdx.y ? biasB : biasF;
  unsigned short* Po = blockIdx.y ? PB : PF;
  __shared__ __align__(16) unsigned short oc[16][1024];
  int r0 = blockIdx.x * 16;
  int tid = threadIdx.x;
  int w = tid >> 6;
  int lane = tid & 63;
  int m = lane & 15;
  int q = lane >> 4;
  const float* ew = wemb + (size_t)tok[r0 + m] * 256 + (q << 3);
  f32x4 z = {0.f, 0.f, 0.f, 0.f};
  f32x4 ac[16] = {z, z, z, z, z, z, z, z, z, z, z, z, z, z, z, z};
  for (int kt = 0; kt < 8; ++kt) {
    float4 e0 = *reinterpret_cast<const float4*>(ew + (kt << 5));
    float4 e1 = *reinterpret_cast<const float4*>(ew + (kt << 5) + 4);
    union { unsigned short us[8]; short8 v; } af;
    af.us[0] = f2bf(e0.x); af.us[1] = f2bf(e0.y); af.us[2] = f2bf(e0.z); af.us[3] = f2bf(e0.w);
    af.us[4] = f2bf(e1.x); af.us[5] = f2bf(e1.y); af.us[6] = f2bf(e1.z); af.us[7] = f2bf(e1.w);
#pragma unroll
    for (int j = 0; j < 16; ++j) {
      int nt = (w << 4) + j;
      uint4 b4 = Wp[(size_t)(nt * 8 + kt) * 64 + lane];
      ac[j] = __builtin_amdgcn_mfma_f32_16x16x32_bf16(af.v, __builtin_bit_cast(short8, b4), ac[j], 0, 0, 0);
    }
  }
  // stage into P-packed LDS tile: for wave w, g = w
#pragma unroll
  for (int j = 0; j < 16; ++j) {
    int col = (w << 8) + (j << 4) + m;
    float bv = bi[col];
    int cellp = ((j >> 1) << 4) | m;          // (wl<<4)|mm
    int sub = (w << 1) | (j & 1);             // (g<<1)|nn
#pragma unroll
    for (int reg = 0; reg < 4; ++reg) {
      int row = (q << 2) + reg;
      oc[row][(cellp << 3) + sub] = f2bf(ac[j][reg] + bv);
    }
  }
  __syncthreads();
  // coalesced copy-out: 16 rows x 2KB
  int b = r0 >> 7;
  unsigned short* Pb = Po + ((size_t)b << 17);
#pragma unroll
  for (int i = 0; i < 8; ++i) {
    int idx = i * 256 + tid;
    int row = idx >> 7;
    int c8 = idx & 127;
    uint4 v = *reinterpret_cast<const uint4*>(&oc[row][c8 << 3]);
    int t = (r0 + row) & 127;
    *reinterpret_cast<uint4*>(Pb + ((size_t)t << 10) + (c8 << 3)) = v;
  }
}

// ---------------- LSTM v15: half-barrier split-h pipeline (unchanged, control) ----
__global__ __launch_bounds__(512, 2) void k_lstm(
    const unsigned short* __restrict__ Pf, const unsigned short* __restrict__ Pb,
    const unsigned int* __restrict__ wpkf, const unsigned int* __restrict__ wpkb,
    unsigned short* __restrict__ hsf, unsigned short* __restrict__ hsb) {
  int bid = blockIdx.x;
  int dir = bid >> 4;
  int b = bid & 15;
  const unsigned short* P = (dir ? Pb : Pf) + ((size_t)b << 17);
  const unsigned int* wpk = dir ? wpkb : wpkf;
  unsigned short* hseq = (dir ? hsb : hsf) + (size_t)b * 128 * 256;

  __shared__ __align__(16) unsigned char h8[2][272];   // fp8 h, double-buffered

  int tid = threadIdx.x;
  int w = tid >> 6;
  int lane = tid & 63;
  int m = lane & 15;
  int q = lane >> 4;
  int nsel = q & 1;
  int jj = (w << 5) + m + (nsel << 4);
  bool lowg = (w < 4);

  i32x8 wfr[4][2][2];
#pragma unroll
  for (int g = 0; g < 4; ++g)
#pragma unroll
    for (int n = 0; n < 2; ++n)
#pragma unroll
      for (int kt = 0; kt < 2; ++kt) {
        int f = (((g << 4) + (w << 1) + n) << 1) + kt;
        wfr[g][n][kt] = *reinterpret_cast<const i32x8*>(wpk + (((size_t)(f << 6) + lane) << 3));
      }
#pragma unroll
  for (int g = 0; g < 4; ++g)
#pragma unroll
    for (int n = 0; n < 2; ++n)
#pragma unroll
      for (int kt = 0; kt < 2; ++kt)
        asm volatile("" : "+v"(wfr[g][n][kt]));

  if (tid < 136) reinterpret_cast<unsigned int*>(&h8[0][0])[tid] = 0u;
  __syncthreads();

  const f32x4 zero4 = {0.f, 0.f, 0.f, 0.f};
  float cst = 0.f;

  auto load_x = [&](int s) -> uint4 {
    int t = dir ? (127 - (s & 127)) : (s & 127);
    return *reinterpret_cast<const uint4*>(
        P + ((size_t)((t << 7) + (w << 4) + m) << 3));
  };

  i32x8 afr0, afr1;
  {
    const unsigned char* cur = &h8[0][0];
    union { uint4 u[2]; i32x8 v; } t0, t1;
    t0.u[0] = *reinterpret_cast<const uint4*>(cur + q * 32);
    t0.u[1] = *reinterpret_cast<const uint4*>(cur + q * 32 + 16);
    t1.u[0] = *reinterpret_cast<const uint4*>(cur + 128 + q * 32);
    t1.u[1] = *reinterpret_cast<const uint4*>(cur + 128 + q * 32 + 16);
    afr0 = t0.v;
    afr1 = t1.v;
  }

  auto gates = [&](const f32x4 acg[4][2], uint4 x4, int t,
                   unsigned char* nxt) {
    unsigned u0 = x4.x, u1 = x4.y, u2 = x4.z, u3 = x4.w;
    float x0 = __uint_as_float(nsel ? (u0 & 0xffff0000u) : (u0 << 16));
    float x1 = __uint_as_float(nsel ? (u1 & 0xffff0000u) : (u1 << 16));
    float x2 = __uint_as_float(nsel ? (u2 & 0xffff0000u) : (u2 << 16));
    float x3 = __uint_as_float(nsel ? (u3 & 0xffff0000u) : (u3 << 16));
    float gi = (nsel ? acg[0][1][0] : acg[0][0][0]) + x0;
    float gf = (nsel ? acg[1][1][0] : acg[1][0][0]) + x1;
    float gg = (nsel ? acg[2][1][0] : acg[2][0][0]) + x2;
    float go = (nsel ? acg[3][1][0] : acg[3][0][0]) + x3;
    float si = __fdividef(1.f, 1.f + __expf(-gi));
    float sf = __fdividef(1.f, 1.f + __expf(-gf));
    float so = __fdividef(1.f, 1.f + __expf(-go));
    float tg = 1.f - __fdividef(2.f, __expf(2.f * gg) + 1.f);
    float cc = sf * cst + si * tg;
    cst = cc;
    float th = 1.f - __fdividef(2.f, __expf(2.f * cc) + 1.f);
    float h = so * th;
    if (q < 2) {
      hseq[(size_t)t * 256 + jj] = f2bf(h);
      int pk = __builtin_amdgcn_cvt_pk_fp8_f32(h, h, 0, false);
      nxt[jj] = (unsigned char)(pk & 0xff);
    }
  };

  auto step = [&](int s, uint4 x4) {
    int t = dir ? (127 - s) : s;
    unsigned char* nxt = &h8[(s & 1) ^ 1][0];

    f32x4 acg[4][2];
#pragma unroll
    for (int n = 0; n < 2; ++n) {
#pragma unroll
      for (int g = 0; g < 4; ++g)
        acg[g][n] = __builtin_amdgcn_mfma_scale_f32_16x16x128_f8f6f4(
            afr0, wfr[g][n][0], zero4, 0, 0, 0, 0x7f7f7f7f, 0, 0x7f7f7f7f);
#pragma unroll
      for (int g = 0; g < 4; ++g)
        acg[g][n] = __builtin_amdgcn_mfma_scale_f32_16x16x128_f8f6f4(
            afr1, wfr[g][n][1], acg[g][n], 0, 0, 0, 0x7f7f7f7f, 0, 0x7f7f7f7f);
    }

    if (lowg) {
      gates(acg, x4, t, nxt);
      asm volatile("s_waitcnt lgkmcnt(0)" ::: "memory");
      __builtin_amdgcn_s_barrier();                       // BarL
      asm volatile("" ::: "memory");
      union { uint4 u[2]; i32x8 v; } t0;
      t0.u[0] = *reinterpret_cast<const uint4*>(nxt + q * 32);
      t0.u[1] = *reinterpret_cast<const uint4*>(nxt + q * 32 + 16);
      asm volatile("" ::: "memory");
      __builtin_amdgcn_s_barrier();                       // BarH
      asm volatile("" ::: "memory");
      union { uint4 u[2]; i32x8 v; } t1;
      t1.u[0] = *reinterpret_cast<const uint4*>(nxt + 128 + q * 32);
      t1.u[1] = *reinterpret_cast<const uint4*>(nxt + 128 + q * 32 + 16);
      afr0 = t0.v;
      afr1 = t1.v;
    } else {
      asm volatile("" ::: "memory");
      __builtin_amdgcn_s_barrier();                       // BarL
      asm volatile("" ::: "memory");
      union { uint4 u[2]; i32x8 v; } t0;
      t0.u[0] = *reinterpret_cast<const uint4*>(nxt + q * 32);
      t0.u[1] = *reinterpret_cast<const uint4*>(nxt + q * 32 + 16);
      gates(acg, x4, t, nxt);
      asm volatile("s_waitcnt lgkmcnt(0)" ::: "memory");
      __builtin_amdgcn_s_barrier();                       // BarH
      asm volatile("" ::: "memory");
      union { uint4 u[2]; i32x8 v; } t1;
      t1.u[0] = *reinterpret_cast<const uint4*>(nxt + 128 + q * 32);
      t1.u[1] = *reinterpret_cast<const uint4*>(nxt + 128 + q * 32 + 16);
      afr0 = t0.v;
      afr1 = t1.v;
    }
  };

  uint4 xA = load_x(0);
  for (int sp = 0; sp < 128; sp += 2) {
    uint4 xB = load_x(sp + 1);
    step(sp, xA);
    xA = load_x(sp + 2);
    step(sp + 1, xB);
  }
}

// ---------------- mid v2: 128 blocks x 16 rows: oc -> emi, u,v -> a,c ----------------
__global__ __launch_bounds__(256) void k_mid2(
    const unsigned short* __restrict__ hf16, const unsigned short* __restrict__ hb16,
    const int* __restrict__ bio, const float* __restrict__ bioE,
    const float* __restrict__ emiW, const float* __restrict__ emib,
    const uint4* __restrict__ suPk, const float* __restrict__ sub,
    const uint4* __restrict__ svPk, const float* __restrict__ svb,
    const uint4* __restrict__ w1Pk, const uint4* __restrict__ w2Pk,
    unsigned short* __restrict__ a16, unsigned short* __restrict__ c16,
    float* __restrict__ emi) {
  __shared__ __align__(16) unsigned short oc[16][328];
  __shared__ __align__(16) unsigned short ub[16][136];
  __shared__ __align__(16) unsigned short vb[16][136];
  int r0 = blockIdx.x * 16;
  int tid = threadIdx.x;

#pragma unroll
  for (int it = 0; it < 8; ++it) {
    int i = it * 256 + tid;
    int row = i >> 7, h2 = (i & 127) << 1;
    unsigned int af = *reinterpret_cast<const unsigned int*>(hf16 + (size_t)(r0 + row) * 256 + h2);
    unsigned int ab = *reinterpret_cast<const unsigned int*>(hb16 + (size_t)(r0 + row) * 256 + h2);
    float lo = 0.5f * (bf2f((unsigned short)af) + bf2f((unsigned short)ab));
    float hi = 0.5f * (bf2f((unsigned short)(af >> 16)) + bf2f((unsigned short)(ab >> 16)));
    unsigned int pk = (unsigned int)f2bf(lo) | ((unsigned int)f2bf(hi) << 16);
    *reinterpret_cast<unsigned int*>(&oc[row][h2]) = pk;
  }
#pragma unroll
  for (int it = 0; it < 2; ++it) {
    int i = it * 256 + tid;
    int row = i >> 5, p = (i & 31) << 1;
    int bi = bio[r0 + row];
    float b0 = bioE[bi * 64 + p], b1 = bioE[bi * 64 + p + 1];
    unsigned int pk = (unsigned int)f2bf(b0) | ((unsigned int)f2bf(b1) << 16);
    *reinterpret_cast<unsigned int*>(&oc[row][256 + p]) = pk;
  }
  __syncthreads();

  if (tid < 192) {
    int did = tid >> 2, sub4 = tid & 3;
    int row = did / 3, g = did - row * 3;
    const float* ew = emiW + g * 256 + sub4 * 64;
    float av = 0.f;
#pragma unroll
    for (int k = 0; k < 64; ++k) av += bf2f(oc[row][sub4 * 64 + k]) * ew[k];
    av += __shfl_xor(av, 1);
    av += __shfl_xor(av, 2);
    if (sub4 == 0) emi[(size_t)(r0 + row) * 3 + g] = av + emib[g];
  }

  int w = tid >> 6, lane = tid & 63, m = lane & 15, q = lane >> 4;
  {
    f32x4 z = {0.f, 0.f, 0.f, 0.f};
    f32x4 au[2] = {z, z}, av2[2] = {z, z};
    for (int kt = 0; kt < 10; ++kt) {
      uint4 a4 = *reinterpret_cast<const uint4*>(&oc[m][(kt << 5) + (q << 3)]);
      short8 af = __builtin_bit_cast(short8, a4);
#pragma unroll
      for (int d = 0; d < 2; ++d) {
        int nt = (w << 1) + d;
        uint4 bu = suPk[(size_t)(nt * 10 + kt) * 64 + lane];
        uint4 bv = svPk[(size_t)(nt * 10 + kt) * 64 + lane];
        au[d] = __builtin_amdgcn_mfma_f32_16x16x32_bf16(af, __builtin_bit_cast(short8, bu), au[d], 0, 0, 0);
        av2[d] = __builtin_amdgcn_mfma_f32_16x16x32_bf16(af, __builtin_bit_cast(short8, bv), av2[d], 0, 0, 0);
      }
    }
#pragma unroll
    for (int d = 0; d < 2; ++d) {
      int col = ((w << 1) + d) * 16 + m;
      float bu = sub[col], bv = svb[col];
#pragma unroll
      for (int reg = 0; reg < 4; ++reg) {
        int row = (q << 2) + reg;
        ub[row][col] = f2bf(fmaxf(au[d][reg] + bu, 0.f));
        vb[row][col] = f2bf(fmaxf(av2[d][reg] + bv, 0.f));
      }
    }
  }
  __syncthreads();

  {
    f32x4 z = {0.f, 0.f, 0.f, 0.f};
    f32x4 aa[2] = {z, z}, cc[2] = {z, z};
    for (int kt = 0; kt < 4; ++kt) {
      uint4 ua = *reinterpret_cast<const uint4*>(&ub[m][(kt << 5) + (q << 3)]);
      uint4 va = *reinterpret_cast<const uint4*>(&vb[m][(kt << 5) + (q << 3)]);
      short8 uf = __builtin_bit_cast(short8, ua);
      short8 vf = __builtin_bit_cast(short8, va);
#pragma unroll
      for (int d = 0; d < 2; ++d) {
        int nt = (w << 1) + d;
        uint4 b1 = w1Pk[(size_t)((nt << 2) + kt) * 64 + lane];
        uint4 b2 = w2Pk[(size_t)((nt << 2) + kt) * 64 + lane];
        aa[d] = __builtin_amdgcn_mfma_f32_16x16x32_bf16(uf, __builtin_bit_cast(short8, b1), aa[d], 0, 0, 0);
        cc[d] = __builtin_amdgcn_mfma_f32_16x16x32_bf16(vf, __builtin_bit_cast(short8, b2), cc[d], 0, 0, 0);
      }
    }
#pragma unroll
    for (int d = 0; d < 2; ++d) {
      int col = ((w << 1) + d) * 16 + m;
#pragma unroll
      for (int reg = 0; reg < 4; ++reg) {
        int row = r0 + (q << 2) + reg;
        a16[(size_t)row * 128 + col] = f2bf(aa[d][reg]);
        c16[(size_t)row * 128 + col] = f2bf(cc[d][reg]);
      }
    }
  }
}

// ---------------- fused loss v3b: sel (0..511, 4 i's/block, j-major LDS,
// u32 reads only — 276B row stride is NOT 16B-aligned, so no uint4/b128!) +
// crf (512..527) + finalize ----------
__global__ __launch_bounds__(256) void k_loss(
    const unsigned short* __restrict__ a16, const unsigned short* __restrict__ c16,
    const float* __restrict__ suvb, const float* __restrict__ rel,
    const float* __restrict__ y, const int* __restrict__ tok,
    const float* __restrict__ emi, const int* __restrict__ bio,
    const float* __restrict__ cstart, const float* __restrict__ cend,
    const float* __restrict__ ctrans,
    float* __restrict__ acc, float* __restrict__ out) {
  int blk = blockIdx.x;
  int tid = threadIdx.x;
  if (blk < 512) {
    // j-major a-tile: aldsT[j][h]; row stride 138 u16 = 69 dwords (odd ->
    // u32 reads land 2 lanes/bank = conflict-free). All LDS accesses are
    // u32-granular: 4-byte aligned everywhere (69-dword stride breaks 8/16B
    // alignment, so b64/b128 reads are ILLEGAL here — r7 lesson).
    __shared__ unsigned short aldsT[128][138];
    __shared__ float cbs[4][128];
    __shared__ float red[4];
    int b = blk >> 5;            // 0..15
    int ip4 = blk & 31;          // 0..31 -> i base = 4*ip4
    int j = tid & 127;
    int half = tid >> 7;         // 0,1
    // stage a16[b, jrow, :] into aldsT[jrow][h] (8192 u32, coalesced, conflict-free)
#pragma unroll
    for (int it = 0; it < 32; ++it) {
      int idx = it * 256 + tid;
      int jrow = idx >> 6;
      int h2 = (idx & 63) << 1;
      unsigned int av = *reinterpret_cast<const unsigned int*>(
          a16 + ((size_t)(b << 7) + jrow) * 128 + h2);
      *reinterpret_cast<unsigned int*>(&aldsT[jrow][h2]) = av;
    }
    // stage cbs[ii][h] = c16[b, 4*ip4+ii, h] + suvb[h]  (ii = 0..3)
#pragma unroll
    for (int it = 0; it < 2; ++it) {
      int ii = (it << 1) + half;
      int h = tid & 127;
      cbs[ii][h] = bf2f(c16[(size_t)((b << 7) + (ip4 << 2) + ii) * 128 + h]) + suvb[h];
    }
    __syncthreads();
    float mj = (tok[(b << 7) + j] != 0) ? 1.f : 0.f;
    float bs = 0.f;
#pragma unroll
    for (int pass = 0; pass < 2; ++pass) {
      int ii = (pass << 1) + half;           // 0..3
      int i = (ip4 << 2) + ii;
      float lg[25];
#pragma unroll
      for (int r = 0; r < 25; ++r) lg[r] = 0.f;
      for (int h8 = 0; h8 < 16; ++h8) {
        // 4 aligned u32 reads (NOT uint4: row base only 4B-aligned)
        const unsigned int* rp =
            reinterpret_cast<const unsigned int*>(&aldsT[j][h8 << 3]);
        unsigned ua0 = rp[0];
        unsigned ua1 = rp[1];
        unsigned ua2 = rp[2];
        unsigned ua3 = rp[3];
        unsigned ua[4] = {ua0, ua1, ua2, ua3};
#pragma unroll
        for (int k = 0; k < 4; ++k) {
          int h0 = (h8 << 3) + (k << 1);
          float av0 = __uint_as_float(ua[k] << 16);
          float av1 = __uint_as_float(ua[k] & 0xffff0000u);
          float uv0 = fmaxf(av0 + cbs[ii][h0], 0.f);
          float uv1 = fmaxf(av1 + cbs[ii][h0 + 1], 0.f);
#pragma unroll
          for (int r = 0; r < 25; ++r) {
            lg[r] += uv0 * rel[r * 128 + h0];
            lg[r] += uv1 * rel[r * 128 + h0 + 1];
          }
        }
      }
      float mi = (tok[(b << 7) + i] != 0) ? 1.f : 0.f;
      const float* yp = y + (size_t)((b << 7) + i) * 3200 + j;
      float bsl = 0.f;
#pragma unroll
      for (int r = 0; r < 25; ++r) {
        float x = lg[r];
        float yv = yp[r * 128];
        bsl += fmaxf(x, 0.f) - x * yv + __logf(1.f + __expf(-fabsf(x)));
      }
      bs += bsl * (mi * mj);
    }
#pragma unroll
    for (int off = 32; off; off >>= 1) bs += __shfl_down(bs, off);
    if ((tid & 63) == 0) red[tid >> 6] = bs;
    __syncthreads();
    if (tid == 0) atomicAdd(&acc[0], red[0] + red[1] + red[2] + red[3]);
  } else {
    __shared__ float elds[128][4];
    __shared__ float msk[128];
    __shared__ int biol[128];
    __shared__ float r_t[2], r_m[2];
    int b = blk - 512;
    int t = tid;
    if (t < 128) {
      biol[t] = bio[b * 128 + t];
      msk[t] = (tok[b * 128 + t] != 0) ? 1.f : 0.f;
#pragma unroll
      for (int g = 0; g < 3; ++g) elds[t][g] = emi[(b * 128 + t) * 3 + g];
    }
    __syncthreads();
    if (t < 128) {
      float m = msk[t];
      float term;
      if (t == 0)
        term = cstart[biol[0]] + elds[0][biol[0]];
      else
        term = (ctrans[biol[t - 1] * 3 + biol[t]] + elds[t][biol[t]]) * m;
      float ms = m;
#pragma unroll
      for (int off = 32; off; off >>= 1) {
        term += __shfl_down(term, off);
        ms += __shfl_down(ms, off);
      }
      if ((t & 63) == 0) { r_t[t >> 6] = term; r_m[t >> 6] = ms; }
    }
    __syncthreads();
    if (t == 0) {
      float num = r_t[0] + r_t[1];
      float msum = r_m[0] + r_m[1];
      int se = (int)msum - 1;
      if (se < 0) se = 0;
      num += cend[biol[se]];
      float tr[9];
#pragma unroll
      for (int i2 = 0; i2 < 9; ++i2) tr[i2] = ctrans[i2];
      float s0 = cstart[0] + elds[0][0];
      float s1 = cstart[1] + elds[0][1];
      float s2 = cstart[2] + elds[0][2];
      for (int tt = 1; tt < 128; ++tt) {
        float a0, a1, a2, mx, n0, n1, n2;
        a0 = s0 + tr[0]; a1 = s1 + tr[3]; a2 = s2 + tr[6];
        mx = fmaxf(a0, fmaxf(a1, a2));
        n0 = mx + __logf(__expf(a0 - mx) + __expf(a1 - mx) + __expf(a2 - mx)) + elds[tt][0];
        a0 = s0 + tr[1]; a1 = s1 + tr[4]; a2 = s2 + tr[7];
        mx = fmaxf(a0, fmaxf(a1, a2));
        n1 = mx + __logf(__expf(a0 - mx) + __expf(a1 - mx) + __expf(a2 - mx)) + elds[tt][1];
        a0 = s0 + tr[2]; a1 = s1 + tr[5]; a2 = s2 + tr[8];
        mx = fmaxf(a0, fmaxf(a1, a2));
        n2 = mx + __logf(__expf(a0 - mx) + __expf(a1 - mx) + __expf(a2 - mx)) + elds[tt][2];
        if (msk[tt] != 0.f) { s0 = n0; s1 = n1; s2 = n2; }
      }
      float a0 = s0 + cend[0], a1 = s1 + cend[1], a2 = s2 + cend[2];
      float mx = fmaxf(a0, fmaxf(a1, a2));
      float den = mx + __logf(__expf(a0 - mx) + __expf(a1 - mx) + __expf(a2 - mx));
      atomicAdd(&acc[1], num - den);
      atomicAdd(&acc[2], msum);
    }
  }
  if (tid == 0) {
    __threadfence();
    unsigned old = atomicAdd((unsigned int*)(acc + 5), 1u);
    if (old == 527u) {
      __threadfence();
      float s0 = atomicAdd(&acc[0], 0.f);
      float s1 = atomicAdd(&acc[1], 0.f);
      float s2 = atomicAdd(&acc[2], 0.f);
      out[0] = -(s1 * (1.f / 16.f)) + s0 / s2;
    }
  }
}

// ---------------- host launcher ----------------
extern "C" void kernel_launch(void* const* d_in, const int* in_sizes, int n_in,
                              void* d_out, int out_size, void* d_ws, size_t ws_size,
                              hipStream_t stream) {
  const int* tokens = (const int*)d_in[0];
  const int* bio = (const int*)d_in[1];
  const float* selg = (const float*)d_in[2];
  const float* wemb = (const float*)d_in[3];
  const float* Wihf = (const float*)d_in[4];
  const float* Whhf = (const float*)d_in[5];
  const float* bf = (const float*)d_in[6];
  const float* Wihb = (const float*)d_in[7];
  const float* Whhb = (const float*)d_in[8];
  const float* bb = (const float*)d_in[9];
  const float* emiW = (const float*)d_in[10];
  const float* emib = (const float*)d_in[11];
  const float* bioE = (const float*)d_in[12];
  const float* suW = (const float*)d_in[13];
  const float* sub = (const float*)d_in[14];
  const float* svW = (const float*)d_in[15];
  const float* svb = (const float*)d_in[16];
  const float* suvW = (const float*)d_in[17];
  const float* suvb = (const float*)d_in[18];
  const float* rel = (const float*)d_in[19];
  const float* cstart = (const float*)d_in[20];
  const float* cend = (const float*)d_in[21];
  const float* ctrans = (const float*)d_in[22];

  float* ws = (float*)d_ws;
  float* xgf16 = ws;                         // 1048576 f = 4MB: P-packed xg fwd
  float* xgb16 = xgf16 + 1048576;            // P-packed xg bwd
  float* hf16 = xgb16 + 1048576;             // 262144 f (2048x256 bf16)
  float* hb16 = hf16 + 262144;               // 262144
  float* a16 = hb16 + 262144;                // 131072 f (2048x128 bf16)
  float* c16 = a16 + 131072;                 // 131072
  float* emi = c16 + 131072;                 // 6144
  float* wpk8f = emi + 6144;                 // 65536 f (256 KB fp8 K=128 frags)
  float* wpk8b = wpk8f + 65536;              // 65536
  float* wihfPk = wpk8b + 65536;             // 131072 f
  float* wihbPk = wihfPk + 131072;           // 131072
  float* suPk = wihbPk + 131072;             // 20480 f
  float* svPk = suPk + 20480;                // 20480
  float* w1Pk = svPk + 20480;                // 8192 f
  float* w2Pk = w1Pk + 8192;                 // 8192
  float* acc = w2Pk + 8192;                  // 16

  k_setup<<<569, 256, 0, stream>>>(
      Whhf, (unsigned int*)wpk8f, Whhb, (unsigned int*)wpk8b,
      Wihf, (uint4*)wihfPk, Wihb, (uint4*)wihbPk,
      suW, (uint4*)suPk, svW, (uint4*)svPk,
      suvW, (uint4*)w1Pk, (uint4*)w2Pk, acc);

  k_xg<<<dim3(128, 2), 256, 0, stream>>>(
      tokens, wemb,
      (const uint4*)wihfPk, bf, (unsigned short*)xgf16,
      (const uint4*)wihbPk, bb, (unsigned short*)xgb16);

  k_lstm<<<32, 512, 0, stream>>>(
      (const unsigned short*)xgf16, (const unsigned short*)xgb16,
      (const unsigned int*)wpk8f, (const unsigned int*)wpk8b,
      (unsigned short*)hf16, (unsigned short*)hb16);

  k_mid2<<<128, 256, 0, stream>>>(
      (const unsigned short*)hf16, (const unsigned short*)hb16,
      bio, bioE, emiW, emib,
      (const uint4*)suPk, sub, (const uint4*)svPk, svb,
      (const uint4*)w1Pk, (const uint4*)w2Pk,
      (unsigned short*)a16, (unsigned short*)c16, emi);

  k_loss<<<528, 256, 0, stream>>>((const unsigned short*)a16, (const unsigned short*)c16,
                                  suvb, rel, selg, tokens, emi, bio,
                                  cstart, cend, ctrans, acc, (float*)d_out);
}